// Round 1
// baseline (492.661 us; speedup 1.0000x reference)
//
#include <hip/hip_runtime.h>

#define T_LEN 16384
#define BIGF 1e30f

// Returns c0 = softplus(x); sets c1 = softplus(-x).
// Uses softplus(x) = max(x,0) + log1p(exp(-|x|)) and c0 = c1 + x.
__device__ __forceinline__ float sp_pair(float x, float& c1) {
    float l = log1pf(__expf(-fabsf(x)));
    c1 = fmaxf(-x, 0.0f) + l;   // softplus(-x)
    return c1 + x;              // softplus(x)
}

__global__ void mfl_zero(float* out) {
    if (threadIdx.x == 0) out[0] = 0.0f;
}

__global__ __launch_bounds__(256) void mfl_main(const float* __restrict__ x,
                                                const int* __restrict__ tgt,
                                                float* __restrict__ res,
                                                int total, float inv_total) {
    float acc = 0.0f;
    const int stride = gridDim.x * blockDim.x;
    for (int p = blockIdx.x * blockDim.x + threadIdx.x; p < total; p += stride) {
        const int t = p & (T_LEN - 1);
        const int tg = tgt[p];
        if (tg == 0) {
            // zero target: loss vs 0 = softplus(x)
            float c1;
            acc += sp_pair(x[p], c1);
        } else if (t == 0 || tgt[p - 1] == 0) {
            // segment start: walk the run of ones, doing the 3-state DP.
            // state s = 2*prev2 + prev1; s=0 always infeasible (two zeros in window).
            float c1_0;
            float c0_0 = sp_pair(x[p], c1_0);
            // after first element (reset dp=(BIG,BIG,BIG,0), then transition):
            float v1 = BIGF;      // (0,1)
            float v2 = c0_0;      // (1,0) : leading zero (ones-padding before)
            float v3 = c1_0;      // (1,1) : all ones so far
            float s1 = c1_0;      // plain sum of c1 (forced-ones fallback)
            int len = 1;
            int tt = t + 1, pp = p + 1;
            while (tt < T_LEN && tgt[pp] != 0) {
                float c1;
                float c0 = sp_pair(x[pp], c1);
                float n1 = v2 + c1;               // new (0,1): prev window (1,0,1)
                float n2 = v3 + c0;               // new (1,0): prev window (1,1,0)
                float n3 = fminf(v1, v3) + c1;    // new (1,1)
                v1 = fminf(n1, BIGF);
                v2 = fminf(n2, BIGF);
                v3 = fminf(n3, BIGF);
                s1 += c1;
                ++len; ++tt; ++pp;
            }
            // run length < 3: forced all-ones (sum of c1); else DP min at end
            acc += (len < 3) ? s1 : fminf(v1, fminf(v2, v3));
        }
        // target==1, not a start: contributes nothing here (owned by start thread)
    }

    // wave (64-lane) shuffle reduction
    #pragma unroll
    for (int off = 32; off > 0; off >>= 1)
        acc += __shfl_down(acc, off);

    __shared__ float smem[4];  // 256 threads / 64 lanes
    const int lane = threadIdx.x & 63;
    const int wid = threadIdx.x >> 6;
    if (lane == 0) smem[wid] = acc;
    __syncthreads();
    if (threadIdx.x == 0) {
        float b = (smem[0] + smem[1]) + (smem[2] + smem[3]);
        atomicAdd(res, b * inv_total);  // pre-scaled partial: keeps fp32 atomic error ~1e-6
    }
}

extern "C" void kernel_launch(void* const* d_in, const int* in_sizes, int n_in,
                              void* d_out, int out_size, void* d_ws, size_t ws_size,
                              hipStream_t stream) {
    const float* x = (const float*)d_in[0];
    const int* tgt = (const int*)d_in[1];
    float* res = (float*)d_out;
    const int total = in_sizes[0];  // 1024 * 16384

    mfl_zero<<<1, 64, 0, stream>>>(res);

    const int threads = 256;
    const int blocks = 2048;  // ~8 blocks/CU, grid-stride covers 16.7M elements
    mfl_main<<<blocks, threads, 0, stream>>>(x, tgt, res, total,
                                             1.0f / (float)total);
}

// Round 6
// 166.023 us; speedup vs baseline: 2.9674x; 2.9674x over previous
//
#include <hip/hip_runtime.h>

#define T_LEN 16384
#define K_CHUNK 32
#define BIGF 1e30f

// c0 = softplus(x), c1 = softplus(-x), via hardware exp/log.
// softplus(-x) = max(-x,0) + log(1+exp(-|x|));  c0 = c1 + x.
__device__ __forceinline__ void sp_pair(float xv, float& c0, float& c1) {
    float e = __expf(-fabsf(xv));   // v_exp_f32 (note: __expf uses exp2 scaling internally)
    float l = __logf(1.0f + e);     // v_log_f32; arg in (1,2], well-conditioned
    c1 = fmaxf(-xv, 0.0f) + l;
    c0 = c1 + xv;
}

__global__ void mfl_zero(float* out) {
    if (threadIdx.x == 0) out[0] = 0.0f;
}

__global__ __launch_bounds__(256) void mfl_main(const float* __restrict__ x,
                                                const int* __restrict__ tgt,
                                                float* __restrict__ res,
                                                int total, float inv_total) {
    const int nchunks = total / K_CHUNK;
    const int stride = gridDim.x * blockDim.x;
    float acc = 0.0f;

    for (int c = blockIdx.x * blockDim.x + threadIdx.x; c < nchunks; c += stride) {
        const int p0 = c * K_CHUNK;
        const int trow = p0 & (T_LEN - 1);   // offset of chunk start within its row

        // ---- load chunk: 8x float4 + 8x int4 (128B-aligned), pack targets to bits
        float xs[32];
        unsigned m = 0;
        const float4* xp = (const float4*)(x + p0);
        const int4*  tp = (const int4*)(tgt + p0);
        #pragma unroll
        for (int j = 0; j < 8; j++) {
            float4 v = xp[j];
            xs[4*j+0] = v.x; xs[4*j+1] = v.y; xs[4*j+2] = v.z; xs[4*j+3] = v.w;
        }
        #pragma unroll
        for (int j = 0; j < 8; j++) {
            int4 t = tp[j];
            m |= (unsigned)(t.x != 0) << (4*j+0);
            m |= (unsigned)(t.y != 0) << (4*j+1);
            m |= (unsigned)(t.z != 0) << (4*j+2);
            m |= (unsigned)(t.w != 0) << (4*j+3);
        }

        // ---- head skip: a run continuing from the previous chunk is owned there
        int istart = 0;
        if (trow != 0 && tgt[p0 - 1] != 0) {
            unsigned nm = ~m;
            istart = (nm == 0u) ? 32 : __builtin_ctz(nm);
        }

        // ---- streaming 3-state min-plus DP over the chunk
        // state s = 2*prev2 + prev1; window constraint: every 3-window >= 2 ones
        float v1 = BIGF, v2 = BIGF, v3 = BIGF, s1 = 0.0f;
        int len = 0;
        bool prev_one = false;
        #pragma unroll
        for (int i = 0; i < 32; i++) {
            float c0, c1;
            sp_pair(xs[i], c0, c1);          // uniform, unconditional
            if (i >= istart) {
                bool one = (m >> i) & 1u;
                if (one) {
                    if (!prev_one) {          // segment start: reset + first step
                        v1 = BIGF; v2 = c0; v3 = c1; s1 = c1; len = 1;
                    } else {
                        float n1 = v2 + c1;               // (0,1) <- (1,0)+1
                        float n2 = v3 + c0;               // (1,0) <- (1,1)+0
                        float n3 = fminf(v1, v3) + c1;    // (1,1)
                        v1 = n1; v2 = n2; v3 = n3;
                        s1 += c1; len++;
                    }
                } else {
                    if (prev_one)             // run ended: harvest
                        acc += (len < 3) ? s1 : fminf(v1, fminf(v2, v3));
                    acc += c0;                // zero-target cost
                }
                prev_one = one;
            }
        }

        // ---- tail walk: run started in this chunk continues past chunk end
        if (prev_one) {
            int t = trow + K_CHUNK, pp = p0 + K_CHUNK;
            while (t < T_LEN && tgt[pp] != 0) {
                float c0, c1;
                sp_pair(x[pp], c0, c1);
                float n1 = v2 + c1;
                float n2 = v3 + c0;
                float n3 = fminf(v1, v3) + c1;
                v1 = n1; v2 = n2; v3 = n3;
                s1 += c1; len++;
                t++; pp++;
            }
            acc += (len < 3) ? s1 : fminf(v1, fminf(v2, v3));
        }
    }

    // ---- reduction: wave shuffle tree, LDS across 4 waves, one atomic/block
    #pragma unroll
    for (int off = 32; off > 0; off >>= 1)
        acc += __shfl_down(acc, off);

    __shared__ float smem[4];
    const int lane = threadIdx.x & 63;
    const int wid = threadIdx.x >> 6;
    if (lane == 0) smem[wid] = acc;
    __syncthreads();
    if (threadIdx.x == 0) {
        float b = (smem[0] + smem[1]) + (smem[2] + smem[3]);
        atomicAdd(res, b * inv_total);   // pre-scaled: fp32 atomic error ~1e-6
    }
}

extern "C" void kernel_launch(void* const* d_in, const int* in_sizes, int n_in,
                              void* d_out, int out_size, void* d_ws, size_t ws_size,
                              hipStream_t stream) {
    const float* x = (const float*)d_in[0];
    const int* tgt = (const int*)d_in[1];
    float* res = (float*)d_out;
    const int total = in_sizes[0];        // 1024 * 16384

    mfl_zero<<<1, 64, 0, stream>>>(res);

    const int threads = 256;
    const int nchunks = total / K_CHUNK;  // 524288 threads needed
    const int blocks = (nchunks + threads - 1) / threads;   // 2048
    mfl_main<<<blocks, threads, 0, stream>>>(x, tgt, res, total,
                                             1.0f / (float)total);
}

// Round 7
// 159.596 us; speedup vs baseline: 3.0869x; 1.0403x over previous
//
#include <hip/hip_runtime.h>

#define T_LEN 16384
#define K_CHUNK 32
#define BIGF 1e30f

// c0 = softplus(x), c1 = softplus(-x), via hardware exp/log.
// softplus(-x) = max(-x,0) + log(1+exp(-|x|));  c0 = c1 + x.
__device__ __forceinline__ void sp_pair(float xv, float& c0, float& c1) {
    float e = __expf(-fabsf(xv));   // v_exp_f32 with -abs input modifier
    float l = __logf(1.0f + e);     // v_log_f32; arg in (1,2], well-conditioned
    c1 = fmaxf(-xv, 0.0f) + l;
    c0 = c1 + xv;
}

__global__ void mfl_zero(float* out) {
    if (threadIdx.x == 0) out[0] = 0.0f;
}

__global__ __launch_bounds__(256) void mfl_main(const float* __restrict__ x,
                                                const int* __restrict__ tgt,
                                                float* __restrict__ res,
                                                int total, float inv_total) {
    const int nchunks = total / K_CHUNK;
    const int stride = gridDim.x * blockDim.x;
    float acc = 0.0f;

    for (int c = blockIdx.x * blockDim.x + threadIdx.x; c < nchunks; c += stride) {
        const int p0 = c * K_CHUNK;
        const int trow = p0 & (T_LEN - 1);   // chunk offset within its row (rows divide chunks exactly)

        // ---- load chunk: 8x float4 + 8x int4, pack targets to a 32-bit mask
        float xs[32];
        unsigned m = 0;
        const float4* xp = (const float4*)(x + p0);
        const int4*  tp = (const int4*)(tgt + p0);
        #pragma unroll
        for (int j = 0; j < 8; j++) {
            float4 v = xp[j];
            xs[4*j+0] = v.x; xs[4*j+1] = v.y; xs[4*j+2] = v.z; xs[4*j+3] = v.w;
        }
        #pragma unroll
        for (int j = 0; j < 8; j++) {
            int4 t = tp[j];
            m |= (unsigned)(t.x != 0) << (4*j+0);
            m |= (unsigned)(t.y != 0) << (4*j+1);
            m |= (unsigned)(t.z != 0) << (4*j+2);
            m |= (unsigned)(t.w != 0) << (4*j+3);
        }

        // ---- head-skip as a bitmask: a run continuing from the previous chunk
        // is owned by the thread holding its start; mask off those leading ones.
        unsigned amask = 0xFFFFFFFFu;
        if (trow != 0 && tgt[p0 - 1] != 0) {
            unsigned nm = ~m;
            amask = (nm == 0u) ? 0u : (0xFFFFFFFFu << __builtin_ctz(nm));
        }
        const unsigned mm = m & amask;       // active ones
        const unsigned zm = (~m) & amask;    // active zeros

        // ---- branchless streaming 3-state min-plus DP (state = dp[1],dp[2],dp[3])
        // Transition runs UNCONDITIONALLY every element; between runs the state is
        // dead (next segment start resets it), so corruption is harmless.
        float v1 = BIGF, v2 = BIGF, v3 = 0.0f, s1 = 0.0f;
        int   leni = 0;
        unsigned prev = 0;
        #pragma unroll
        for (int i = 0; i < 32; i++) {
            float c0, c1;
            sp_pair(xs[i], c0, c1);
            const unsigned one = (mm >> i) & 1u;
            const unsigned za  = (zm >> i) & 1u;
            // harvest (run ended at i-1): uses pre-update state
            const bool endf = (prev & (one ^ 1u)) != 0u;
            const float hv = (leni < 3) ? s1 : fminf(v1, fminf(v2, v3));
            acc += endf ? hv : 0.0f;
            acc += za ? c0 : 0.0f;           // zero-target cost
            // segment-start reset: dp = (BIG, BIG, 0), s1 = len = 0
            const bool startf = (one & (prev ^ 1u)) != 0u;
            const float r1 = startf ? BIGF : v1;
            const float r2 = startf ? BIGF : v2;
            const float r3 = startf ? 0.0f : v3;
            s1   = startf ? 0.0f : s1;
            leni = startf ? 0    : leni;
            // min-plus transition
            v1 = r2 + c1;                    // (0,1) <- (1,0)+one
            v2 = r3 + c0;                    // (1,0) <- (1,1)+zero
            v3 = fminf(r1, r3) + c1;         // (1,1)
            s1 += c1;
            leni += 1;
            prev = one;
        }

        // ---- tail walk (rare): run crosses the chunk end; grouped 4-wide loads.
        if (prev) {
            int t = trow + K_CHUNK, pp = p0 + K_CHUNK;
            while (t < T_LEN) {              // t always 0 mod 4 -> loads stay in-row
                const int4   tq = *(const int4*)(tgt + pp);
                const float4 xq = *(const float4*)(x + pp);
                const unsigned g = (unsigned)(tq.x != 0)
                                 | ((unsigned)(tq.y != 0) << 1)
                                 | ((unsigned)(tq.z != 0) << 2)
                                 | ((unsigned)(tq.w != 0) << 3);
                const int k = (g == 0xFu) ? 4 : (int)__builtin_ctz(~g & 0xFu);
                const float xv[4] = {xq.x, xq.y, xq.z, xq.w};
                #pragma unroll
                for (int j = 0; j < 4; j++) {
                    if (j < k) {
                        float c0, c1;
                        sp_pair(xv[j], c0, c1);
                        const float n1 = v2 + c1;
                        const float n2 = v3 + c0;
                        const float n3 = fminf(v1, v3) + c1;
                        v1 = n1; v2 = n2; v3 = n3;
                        s1 += c1; leni++;
                    }
                }
                if (k < 4) break;            // hit the run-terminating zero
                t += 4; pp += 4;
            }
            acc += (leni < 3) ? s1 : fminf(v1, fminf(v2, v3));
        }
    }

    // ---- reduction: wave shuffle tree, LDS across 4 waves, one atomic/block
    #pragma unroll
    for (int off = 32; off > 0; off >>= 1)
        acc += __shfl_down(acc, off);

    __shared__ float smem[4];
    const int lane = threadIdx.x & 63;
    const int wid = threadIdx.x >> 6;
    if (lane == 0) smem[wid] = acc;
    __syncthreads();
    if (threadIdx.x == 0) {
        float b = (smem[0] + smem[1]) + (smem[2] + smem[3]);
        atomicAdd(res, b * inv_total);   // pre-scaled: fp32 atomic error ~1e-6
    }
}

extern "C" void kernel_launch(void* const* d_in, const int* in_sizes, int n_in,
                              void* d_out, int out_size, void* d_ws, size_t ws_size,
                              hipStream_t stream) {
    const float* x = (const float*)d_in[0];
    const int* tgt = (const int*)d_in[1];
    float* res = (float*)d_out;
    const int total = in_sizes[0];        // 1024 * 16384

    mfl_zero<<<1, 64, 0, stream>>>(res);

    const int threads = 256;
    const int nchunks = total / K_CHUNK;  // 524288 threads
    const int blocks = (nchunks + threads - 1) / threads;   // 2048
    mfl_main<<<blocks, threads, 0, stream>>>(x, tgt, res, total,
                                             1.0f / (float)total);
}

// Round 11
// 155.355 us; speedup vs baseline: 3.1712x; 1.0273x over previous
//
#include <hip/hip_runtime.h>

#define T_LEN 16384
#define K_CHUNK 32
#define BIGF 1e30f

// softplus(x) = max(x,0) + log(1+exp(-|x|)) via hardware v_exp_f32/v_log_f32
__device__ __forceinline__ float sp0(float xv) {
    float e = __expf(-fabsf(xv));
    float l = __logf(1.0f + e);
    return fmaxf(xv, 0.0f) + l;
}

__global__ void mfl_zero(float* out) {
    if (threadIdx.x == 0) out[0] = 0.0f;
}

// Delta formulation: loss = sum_all softplus(x)  +  sum_runs delta(run),
// where delta uses per-element costs {zero-choice: 0, one-choice: -x}
// (subtracting c0 from every DP path element-wise preserves the min).
// Short runs (<3): delta = -sum(x). DP runs: 3-state min-plus on deltas.
__global__ __launch_bounds__(256) void mfl_main(const float* __restrict__ x,
                                                const int* __restrict__ tgt,
                                                float* __restrict__ res,
                                                int total, float inv_total) {
    const int nchunks = total / K_CHUNK;
    const int stride = gridDim.x * blockDim.x;
    float acc = 0.0f;

    for (int c = blockIdx.x * blockDim.x + threadIdx.x; c < nchunks; c += stride) {
        const int p0 = c * K_CHUNK;
        const int trow = p0 & (T_LEN - 1);

        // ---- main chunk loads: 8x float4 + 8x int4, targets -> 32-bit mask
        float xs[32];
        unsigned m = 0;
        const float4* xp = (const float4*)(x + p0);
        const int4*  tp = (const int4*)(tgt + p0);
        #pragma unroll
        for (int j = 0; j < 8; j++) {
            float4 v = xp[j];
            xs[4*j+0] = v.x; xs[4*j+1] = v.y; xs[4*j+2] = v.z; xs[4*j+3] = v.w;
        }
        #pragma unroll
        for (int j = 0; j < 8; j++) {
            int4 t = tp[j];
            m |= (unsigned)(t.x != 0) << (4*j+0);
            m |= (unsigned)(t.y != 0) << (4*j+1);
            m |= (unsigned)(t.z != 0) << (4*j+2);
            m |= (unsigned)(t.w != 0) << (4*j+3);
        }

        // ---- lookahead-8 into next chunk (issued now -> latency overlapped;
        // L2 dedupes vs the neighbor thread's own loads). Safe-clamped at EOT;
        // only ever USED when the row continues past this chunk.
        const int pl = (p0 + K_CHUNK + 8 <= total) ? (p0 + K_CHUNK) : p0;
        float la[8];
        unsigned lm = 0;
        {
            const float4* lxp = (const float4*)(x + pl);
            const int4*  ltp = (const int4*)(tgt + pl);
            float4 a0 = lxp[0], a1 = lxp[1];
            int4   b0 = ltp[0], b1 = ltp[1];
            la[0]=a0.x; la[1]=a0.y; la[2]=a0.z; la[3]=a0.w;
            la[4]=a1.x; la[5]=a1.y; la[6]=a1.z; la[7]=a1.w;
            lm  = (unsigned)(b0.x!=0)      | ((unsigned)(b0.y!=0)<<1)
                | ((unsigned)(b0.z!=0)<<2) | ((unsigned)(b0.w!=0)<<3)
                | ((unsigned)(b1.x!=0)<<4) | ((unsigned)(b1.y!=0)<<5)
                | ((unsigned)(b1.z!=0)<<6) | ((unsigned)(b1.w!=0)<<7);
        }

        // ---- ownership: runs continuing from the previous chunk are owned there
        unsigned amask = 0xFFFFFFFFu;
        if (trow != 0 && tgt[p0 - 1] != 0) {
            unsigned nm = ~m;
            amask = (nm == 0u) ? 0u : (0xFFFFFFFFu << __builtin_ctz(nm));
        }
        const unsigned mm = m & amask;          // owned ones
        const unsigned ss = mm & ~(mm << 1);    // run-start bits
        const unsigned hm = (~mm) & (mm << 1);  // harvest bits (run ended at i-1)

        // ---- branchless delta-DP over the chunk
        float v1 = BIGF, v2 = BIGF, v3 = 0.0f, s1 = 0.0f;
        int leni = 0;
        #pragma unroll
        for (int i = 0; i < 32; i++) {
            const float xv = xs[i];
            acc += sp0(xv);                              // every element's c0, once
            const bool harvf = (hm >> i) & 1u;           // harvest pre-update state
            const float hv = (leni < 3) ? s1 : fminf(v1, fminf(v2, v3));
            acc += harvf ? hv : 0.0f;
            const bool startf = (ss >> i) & 1u;          // segment-start reset
            const float r1 = startf ? BIGF : v1;
            const float r2 = startf ? BIGF : v2;
            const float r3 = startf ? 0.0f : v3;
            const float s1r = startf ? 0.0f : s1;
            const int   lr  = startf ? 0    : leni;
            v1 = r2 - xv;                                // (0,1) <- (1,0) + (-x)
            v2 = r3;                                     // (1,0) <- (1,1) + 0
            v3 = fminf(r1, r3) - xv;                     // (1,1)
            s1 = s1r - xv;
            leni = lr + 1;
        }

        // ---- cross-chunk tail: lookahead covers <=8; serial walk is ~0.4% rare
        if ((mm >> 31) & 1u) {
            if (trow + K_CHUNK < T_LEN) {
                const unsigned g = lm & 0xFFu;
                const int k = (g == 0xFFu) ? 8 : (int)__builtin_ctz(~g & 0xFFu);
                #pragma unroll
                for (int j = 0; j < 8; j++) {
                    if (j < k) {
                        const float xv = la[j];
                        const float n1 = v2 - xv;
                        const float n2 = v3;
                        const float n3 = fminf(v1, v3) - xv;
                        v1 = n1; v2 = n2; v3 = n3;
                        s1 -= xv; leni++;
                    }
                }
                if (k == 8) {                    // run extends past lookahead (rare)
                    int t = trow + K_CHUNK + 8, pp = p0 + K_CHUNK + 8;
                    while (t < T_LEN) {          // 16B-aligned, stays in-row
                        const int4   tq = *(const int4*)(tgt + pp);
                        const float4 xq = *(const float4*)(x + pp);
                        const unsigned g4 = (unsigned)(tq.x != 0)
                                          | ((unsigned)(tq.y != 0) << 1)
                                          | ((unsigned)(tq.z != 0) << 2)
                                          | ((unsigned)(tq.w != 0) << 3);
                        const int k4 = (g4 == 0xFu) ? 4 : (int)__builtin_ctz(~g4 & 0xFu);
                        const float xv4[4] = {xq.x, xq.y, xq.z, xq.w};
                        #pragma unroll
                        for (int j = 0; j < 4; j++) {
                            if (j < k4) {
                                const float xv = xv4[j];
                                const float n1 = v2 - xv;
                                const float n2 = v3;
                                const float n3 = fminf(v1, v3) - xv;
                                v1 = n1; v2 = n2; v3 = n3;
                                s1 -= xv; leni++;
                            }
                        }
                        if (k4 < 4) break;
                        t += 4; pp += 4;
                    }
                }
            }
            acc += (leni < 3) ? s1 : fminf(v1, fminf(v2, v3));
        }
    }

    // ---- reduction: wave shuffle tree, LDS across 4 waves, one atomic/block
    #pragma unroll
    for (int off = 32; off > 0; off >>= 1)
        acc += __shfl_down(acc, off);

    __shared__ float smem[4];
    const int lane = threadIdx.x & 63;
    const int wid = threadIdx.x >> 6;
    if (lane == 0) smem[wid] = acc;
    __syncthreads();
    if (threadIdx.x == 0) {
        float b = (smem[0] + smem[1]) + (smem[2] + smem[3]);
        atomicAdd(res, b * inv_total);   // pre-scaled: fp32 atomic error ~1e-6
    }
}

extern "C" void kernel_launch(void* const* d_in, const int* in_sizes, int n_in,
                              void* d_out, int out_size, void* d_ws, size_t ws_size,
                              hipStream_t stream) {
    const float* x = (const float*)d_in[0];
    const int* tgt = (const int*)d_in[1];
    float* res = (float*)d_out;
    const int total = in_sizes[0];        // 1024 * 16384

    mfl_zero<<<1, 64, 0, stream>>>(res);

    const int threads = 256;
    const int nchunks = total / K_CHUNK;  // 524288 threads
    const int blocks = (nchunks + threads - 1) / threads;   // 2048
    mfl_main<<<blocks, threads, 0, stream>>>(x, tgt, res, total,
                                             1.0f / (float)total);
}